// Round 6
// baseline (866.453 us; speedup 1.0000x reference)
//
#include <hip/hip_runtime.h>
#include <hip/hip_bf16.h>

#define B_ 2
#define C_ 64
#define H_ 128
#define W_ 128
#define HS 64
#define WS 64
#define L_ 4096
#define S_ 4096
#define K1_ 576    // C*3*3
#define NCOL 1024  // C*4*4
#define SCALE_ 10.0f

typedef __attribute__((ext_vector_type(8))) short bf16x8;
typedef __attribute__((ext_vector_type(4))) float f32x4;

// async global->LDS, 16B per lane (wave-uniform LDS base + lane*16).
__device__ __forceinline__ void async_copy16(const void* gsrc, void* ldst) {
    __builtin_amdgcn_global_load_lds(
        (__attribute__((address_space(1))) const void*)gsrc,
        (__attribute__((address_space(3))) void*)ldst, 16, 0, 0);
}

// transposed flat index within a 64x64 grid
__device__ __forceinline__ int TT(int x) { return ((x & 63) << 6) | (x >> 6); }

// fused diag_prop -> T -> diag_prop -> T, evaluated pointwise from raw scores (single batch)
__device__ __forceinline__ float diag9(const float* __restrict__ inb, int l, int s) {
    int tl = TT(l), ts = TT(s);
    float acc = 0.f;
#pragma unroll
    for (int d2 = -1; d2 <= 1; ++d2) {
        int p = tl + d2, q = ts + d2;
        if (p < 0 || p >= 4096 || q < 0 || q >= 4096) continue;
        int l2 = TT(p), s2 = TT(q);
#pragma unroll
        for (int d1 = -1; d1 <= 1; ++d1) {
            int a = l2 + d1, c2 = s2 + d1;
            if (a >= 0 && a < 4096 && c2 >= 0 && c2 < 4096) acc += inb[((size_t)a << 12) + c2];
        }
    }
    return acc;
}

// ---------------- K0a: per-pixel channel sum-of-squares of downsampled bg ----------------
__global__ void k_sumsq(const float* __restrict__ bg, float* __restrict__ ssq) {
    int idx = blockIdx.x * 256 + threadIdx.x;  // B*64*64
    if (idx >= B_ * HS * WS) return;
    int pix = idx & 4095, b = idx >> 12;
    int i = pix >> 6, j = pix & 63;
    float ss = 0.f;
    for (int c = 0; c < C_; ++c) {
        float v = bg[((b * C_ + c) * H_ + 2 * i) * W_ + 2 * j];
        ss += v * v;
    }
    ssq[idx] = ss;
}

// ---------------- K0b: per-patch mask flag + 1/denom (3x3 box) ----------------
__global__ void k_patch_stats(const float* __restrict__ mask, const float* __restrict__ ssq,
                              float* __restrict__ denom_inv, float* __restrict__ maskedf) {
    int idx = blockIdx.x * 256 + threadIdx.x;  // B*L
    if (idx >= B_ * L_) return;
    int b = idx >> 12, l = idx & 4095, lh = l >> 6, lw = l & 63;
    float msum = 0.f, ss = 0.f;
    for (int di = -1; di <= 1; ++di)
        for (int dj = -1; dj <= 1; ++dj) {
            int i = lh + di, j = lw + dj;
            if (i >= 0 && i < HS && j >= 0 && j < WS) {
                msum += mask[(b * H_ + 2 * i) * W_ + 2 * j];
                ss += ssq[(b << 12) + (i << 6) + j];
            }
        }
    maskedf[idx] = (msum == 0.0f) ? 1.0f : 0.0f;
    denom_inv[idx] = 1.0f / fmaxf(sqrtf(ss), 0.001f);
}

// ---------------- K0c: im2col (3x3, pad 1, on 2x-downsampled img) -> hi/lo bf16 [l][576] ----
__global__ void k_im2col(const float* __restrict__ src, __hip_bfloat16* __restrict__ hi,
                         __hip_bfloat16* __restrict__ lo) {
    int idx = blockIdx.x * 256 + threadIdx.x;  // L*576, k fastest
    int k = idx % K1_;
    int l = idx / K1_;
    int c = k / 9, r = k - 9 * c;
    int r3 = r / 3;
    int di = r3 - 1, dj = r - 3 * r3 - 1;
    int i = (l >> 6) + di, j = (l & 63) + dj;
    float v = 0.f;
    if (i >= 0 && i < HS && j >= 0 && j < WS) v = src[(c * H_ + 2 * i) * W_ + 2 * j];
    __hip_bfloat16 h = __float2bfloat16(v);
    hi[idx] = h;
    lo[idx] = __float2bfloat16(v - __bfloat162float(h));
}

// ---------------- K1: scores GEMM, split-bf16 MFMA (fp32-equivalent), single batch --------
__global__ __launch_bounds__(256) void k_gemm1_mfma(const __hip_bfloat16* __restrict__ Ahi,
                                                    const __hip_bfloat16* __restrict__ Alo,
                                                    const __hip_bfloat16* __restrict__ Bhi,
                                                    const __hip_bfloat16* __restrict__ Blo,
                                                    const float* __restrict__ dinv,
                                                    float* __restrict__ scores) {
    __shared__ __hip_bfloat16 AsH[128 * 32], AsL[128 * 32], BsH[128 * 32], BsL[128 * 32];
    int t = threadIdx.x, lane = t & 63, w = t >> 6;
    int wm = w & 1, wn = w >> 1;
    int M0 = blockIdx.y * 128, N0 = blockIdx.x * 128;
    int srow = lane >> 2, schunk = (lane & 3) * 8;
    f32x4 acc[4][4] = {};
    for (int k0 = 0; k0 < K1_; k0 += 32) {
#pragma unroll
        for (int q = 0; q < 2; ++q) {
            int r = q * 64 + w * 16;
            size_t ga = (size_t)(M0 + r + srow) * K1_ + k0 + schunk;
            size_t gb = (size_t)(N0 + r + srow) * K1_ + k0 + schunk;
            int lo_ = r * 32;
            async_copy16(Ahi + ga, &AsH[lo_]);
            async_copy16(Alo + ga, &AsL[lo_]);
            async_copy16(Bhi + gb, &BsH[lo_]);
            async_copy16(Blo + gb, &BsL[lo_]);
        }
        __syncthreads();
        int q8 = (lane >> 4) * 8, mr = lane & 15;
        bf16x8 ah[4], al[4], bh[4], bl[4];
#pragma unroll
        for (int i = 0; i < 4; ++i) {
            int ra = (wm * 64 + i * 16 + mr) * 32 + q8;
            int rb = (wn * 64 + i * 16 + mr) * 32 + q8;
            ah[i] = *(const bf16x8*)&AsH[ra];
            al[i] = *(const bf16x8*)&AsL[ra];
            bh[i] = *(const bf16x8*)&BsH[rb];
            bl[i] = *(const bf16x8*)&BsL[rb];
        }
#pragma unroll
        for (int mt = 0; mt < 4; ++mt)
#pragma unroll
            for (int nt = 0; nt < 4; ++nt) {
                acc[mt][nt] = __builtin_amdgcn_mfma_f32_16x16x32_bf16(ah[mt], bh[nt], acc[mt][nt], 0, 0, 0);
                acc[mt][nt] = __builtin_amdgcn_mfma_f32_16x16x32_bf16(ah[mt], bl[nt], acc[mt][nt], 0, 0, 0);
                acc[mt][nt] = __builtin_amdgcn_mfma_f32_16x16x32_bf16(al[mt], bh[nt], acc[mt][nt], 0, 0, 0);
            }
        __syncthreads();
    }
    int col = lane & 15, rq = (lane >> 4) * 4;
#pragma unroll
    for (int mt = 0; mt < 4; ++mt)
#pragma unroll
        for (int r = 0; r < 4; ++r) {
            int m = M0 + wm * 64 + mt * 16 + rq + r;
            float dv = dinv[m];
#pragma unroll
            for (int nt = 0; nt < 4; ++nt) {
                int n = N0 + wn * 64 + nt * 16 + col;
                scores[(size_t)m * 4096 + n] = acc[mt][nt][r] * dv;
            }
        }
}

// ---------------- K2: per-chunk max of diag9 (no D buffer). grid (16,128), 32 l's/thread --
__global__ __launch_bounds__(256) void k_diag_max(const float* __restrict__ scores,
                                                  const float* __restrict__ maskedf,
                                                  float* __restrict__ pm) {
    int s = blockIdx.x * 256 + threadIdx.x;
    int l0 = blockIdx.y * 32;
    float m0 = -3.0e38f, m1 = -3.0e38f, m2 = -3.0e38f, m3 = -3.0e38f;
#pragma unroll
    for (int i = 0; i < 32; i += 4) {
        float v0 = (maskedf[l0 + i + 0] != 0.f) ? -1000.f : diag9(scores, l0 + i + 0, s);
        float v1 = (maskedf[l0 + i + 1] != 0.f) ? -1000.f : diag9(scores, l0 + i + 1, s);
        float v2 = (maskedf[l0 + i + 2] != 0.f) ? -1000.f : diag9(scores, l0 + i + 2, s);
        float v3 = (maskedf[l0 + i + 3] != 0.f) ? -1000.f : diag9(scores, l0 + i + 3, s);
        m0 = fmaxf(m0, v0);
        m1 = fmaxf(m1, v1);
        m2 = fmaxf(m2, v2);
        m3 = fmaxf(m3, v3);
    }
    pm[((size_t)blockIdx.y << 12) + s] = fmaxf(fmaxf(m0, m1), fmaxf(m2, m3));
}

// ---------------- K3: combine 128 partial maxes -> Mg ----------------
__global__ void k_combine(const float* __restrict__ pm, float* __restrict__ Mg) {
    int s = blockIdx.x * 256 + threadIdx.x;  // 4096
    float a = -3.0e38f, b = -3.0e38f, c = -3.0e38f, d = -3.0e38f;
#pragma unroll
    for (int ch = 0; ch < 128; ch += 4) {
        a = fmaxf(a, pm[((size_t)(ch + 0) << 12) + s]);
        b = fmaxf(b, pm[((size_t)(ch + 1) << 12) + s]);
        c = fmaxf(c, pm[((size_t)(ch + 2) << 12) + s]);
        d = fmaxf(d, pm[((size_t)(ch + 3) << 12) + s]);
    }
    Mg[s] = fmaxf(fmaxf(a, b), fmaxf(c, d));
}

// ---------------- K4: diag9 -> exp -> transpose -> softT[s][l] bf16 (UNNORM) + Z partials -
__global__ __launch_bounds__(256) void k_soft_eT(const float* __restrict__ scores,
                                                 const float* __restrict__ maskedf,
                                                 const float* __restrict__ Mg,
                                                 __hip_bfloat16* __restrict__ softT,
                                                 float* __restrict__ pz) {
    __shared__ float tile[64][65];
    __shared__ float zpart[4][64];
    int t = threadIdx.x;
    int sx = t & 63, tg = t >> 6;
    int s0 = blockIdx.x * 64, l0 = blockIdx.y * 64;
    int s = s0 + sx;
    float mg = Mg[s];
    float zsum = 0.f;
#pragma unroll 4
    for (int i = 0; i < 16; ++i) {
        int lloc = tg * 16 + i;
        int l = l0 + lloc;
        float v = (maskedf[l] != 0.f) ? -1000.f : diag9(scores, l, s);
        float e = __expf(SCALE_ * (v - mg));
        tile[lloc][sx] = e;
        zsum += e;
    }
    zpart[tg][sx] = zsum;
    __syncthreads();
    if (tg == 0) {
        float z = zpart[0][sx] + zpart[1][sx] + zpart[2][sx] + zpart[3][sx];
        pz[((size_t)(l0 >> 6) << 12) + s] = z;
    }
#pragma unroll
    for (int i = 0; i < 16; ++i) {
        int sloc = tg * 16 + i;
        softT[((size_t)(s0 + sloc) << 12) + l0 + sx] = __float2bfloat16(tile[sx][sloc]);
    }
}

// ---------------- K4b: Zinv[s] = 1 / sum of 64 Z partials ----------------
__global__ void k_zinv(const float* __restrict__ pz, float* __restrict__ Zinv) {
    int s = blockIdx.x * 256 + threadIdx.x;  // 4096
    float gz = 0.f;
#pragma unroll
    for (int c = 0; c < 64; ++c) gz += pz[((size_t)c << 12) + s];
    Zinv[s] = 1.0f / gz;
}

// ---------------- K5: cols_T[n][l] bf16 (4x4 bg patches, stride 2, pad 1), single batch ---
__global__ void k_colsT(const float* __restrict__ bgb, __hip_bfloat16* __restrict__ colsT) {
    int idx = blockIdx.x * 256 + threadIdx.x;  // NCOL*L, l fastest
    int l = idx & 4095, n = idx >> 12;
    int kj = n & 3, ki = (n >> 2) & 3, c = n >> 4;
    int y = 2 * (l >> 6) + ki - 1, x = 2 * (l & 63) + kj - 1;
    float v = 0.f;
    if (y >= 0 && y < H_ && x >= 0 && x < W_) v = bgb[(c * H_ + y) * W_ + x];
    colsT[idx] = __float2bfloat16(v);
}

// ---------------- K6: deconv GEMM, bf16 MFMA, 128x64 tiles; epilogue x Zinv[row] ----------
__global__ __launch_bounds__(256) void k_gemm2_mfma(const __hip_bfloat16* __restrict__ softT,
                                                    const __hip_bfloat16* __restrict__ colsT,
                                                    const float* __restrict__ Zinv,
                                                    float* __restrict__ patchT) {
    __shared__ __hip_bfloat16 As[128 * 32], Bs[64 * 32];
    int t = threadIdx.x, lane = t & 63, w = t >> 6;
    int wm = w & 1, wn = w >> 1;
    int M0 = blockIdx.y * 128, N0 = blockIdx.x * 64;
    int srow = lane >> 2, schunk = (lane & 3) * 8;
    f32x4 acc[4][2] = {};
    for (int k0 = 0; k0 < L_; k0 += 32) {
#pragma unroll
        for (int q = 0; q < 2; ++q) {
            int r = q * 64 + w * 16;
            async_copy16(softT + ((size_t)(M0 + r + srow) << 12) + k0 + schunk, &As[r * 32]);
        }
        {
            int r = w * 16;
            async_copy16(colsT + ((size_t)(N0 + r + srow) << 12) + k0 + schunk, &Bs[r * 32]);
        }
        __syncthreads();
        int q8 = (lane >> 4) * 8, mr = lane & 15;
        bf16x8 af[4], bfr[2];
#pragma unroll
        for (int i = 0; i < 4; ++i) af[i] = *(const bf16x8*)&As[(wm * 64 + i * 16 + mr) * 32 + q8];
#pragma unroll
        for (int j = 0; j < 2; ++j) bfr[j] = *(const bf16x8*)&Bs[(wn * 32 + j * 16 + mr) * 32 + q8];
#pragma unroll
        for (int mt = 0; mt < 4; ++mt)
#pragma unroll
            for (int nt = 0; nt < 2; ++nt)
                acc[mt][nt] = __builtin_amdgcn_mfma_f32_16x16x32_bf16(af[mt], bfr[nt], acc[mt][nt], 0, 0, 0);
        __syncthreads();
    }
    int col = lane & 15, rq = (lane >> 4) * 4;
#pragma unroll
    for (int mt = 0; mt < 4; ++mt)
#pragma unroll
        for (int r = 0; r < 4; ++r) {
            int m = M0 + wm * 64 + mt * 16 + rq + r;
            float zi = Zinv[m];
#pragma unroll
            for (int nt = 0; nt < 2; ++nt) {
                int n = N0 + wn * 32 + nt * 16 + col;
                patchT[(size_t)m * 1024 + n] = acc[mt][nt][r] * zi;
            }
        }
}

// ---------------- K7: overlap-add gather (col2im, stride 2, kernel 4, pad 1), single batch
__global__ void k_col2im(const float* __restrict__ patchT, float* __restrict__ outb) {
    int idx = blockIdx.x * 256 + threadIdx.x;  // C*H*W
    if (idx >= C_ * H_ * W_) return;
    int x = idx & 127, y = (idx >> 7) & 127, c = idx >> 14;
    float acc = 0.f;
    int ki0 = (y + 1) & 1, kj0 = (x + 1) & 1;
#pragma unroll
    for (int ki = ki0; ki < 4; ki += 2) {
        int i = (y + 1 - ki) >> 1;
        if (i < 0 || i >= HS) continue;
#pragma unroll
        for (int kj = kj0; kj < 4; kj += 2) {
            int j = (x + 1 - kj) >> 1;
            if (j < 0 || j >= WS) continue;
            acc += patchT[((size_t)(i * 64 + j) << 10) + c * 16 + ki * 4 + kj];
        }
    }
    outb[idx] = acc;
}

extern "C" void kernel_launch(void* const* d_in, const int* in_sizes, int n_in,
                              void* d_out, int out_size, void* d_ws, size_t ws_size,
                              hipStream_t stream) {
    (void)in_sizes; (void)n_in; (void)out_size; (void)ws_size;
    const float* fg = (const float*)d_in[0];
    const float* bg = (const float*)d_in[1];
    const float* mask = (const float*)d_in[2];
    float* out = (float*)d_out;

    // ---- workspace (float offsets); same 156.1 MiB envelope as round 4 ----
    float* ws = (float*)d_ws;
    float* pm = ws;                                              // 524,288 (128 x 4096)
    float* pz = ws + 524288;                                     // 262,144 (64 x 4096)
    float* scores = ws + 16777216;                               // 16,777,216
    __hip_bfloat16* softT = (__hip_bfloat16*)scores;             // alias (scores dead after k_soft_eT... NO:
    // softT must not overwrite scores while k_soft_eT still reads scores. Put softT in former D region.
    float* patchT = ws + 25165824;                               // second half of scores region (scores dead by gemm2)
    __hip_bfloat16* colsT = (__hip_bfloat16*)(ws + 33554432);    // 4,194,304 bf16
    __hip_bfloat16* bgcol_hi = (__hip_bfloat16*)(ws + 35651584); // 2,359,296 bf16 each
    __hip_bfloat16* bgcol_lo = (__hip_bfloat16*)(ws + 36831232);
    __hip_bfloat16* fgcol_hi = (__hip_bfloat16*)(ws + 38010880);
    __hip_bfloat16* fgcol_lo = (__hip_bfloat16*)(ws + 39190528);
    float* denom_inv = ws + 40370176;  // 8,192 (B*L)
    float* maskedf = ws + 40378368;    // 8,192 (B*L)
    float* ssq = ws + 40386560;        // 8,192
    float* Mg = ws + 40394752;         // 4,096
    float* Zinv = ws + 40398848;       // 4,096
    softT = (__hip_bfloat16*)(ws + 1048576);  // 33,554,432 bf16 in former D region (disjoint from scores)

    k_sumsq<<<(B_ * HS * WS) / 256, 256, 0, stream>>>(bg, ssq);
    k_patch_stats<<<(B_ * L_) / 256, 256, 0, stream>>>(mask, ssq, denom_inv, maskedf);

    for (int b = 0; b < B_; ++b) {
        const float* bgb = bg + (size_t)b * C_ * H_ * W_;
        const float* fgb = fg + (size_t)b * C_ * H_ * W_;

        k_im2col<<<(L_ * K1_) / 256, 256, 0, stream>>>(bgb, bgcol_hi, bgcol_lo);
        k_im2col<<<(L_ * K1_) / 256, 256, 0, stream>>>(fgb, fgcol_hi, fgcol_lo);
        k_colsT<<<(NCOL * L_) / 256, 256, 0, stream>>>(bgb, colsT);

        dim3 g1(32, 32);
        k_gemm1_mfma<<<g1, 256, 0, stream>>>(bgcol_hi, bgcol_lo, fgcol_hi, fgcol_lo,
                                             denom_inv + b * L_, scores);

        dim3 g2(16, 128);
        k_diag_max<<<g2, 256, 0, stream>>>(scores, maskedf + b * L_, pm);
        k_combine<<<16, 256, 0, stream>>>(pm, Mg);
        dim3 g4(64, 64);
        k_soft_eT<<<g4, 256, 0, stream>>>(scores, maskedf + b * L_, Mg, softT, pz);
        k_zinv<<<16, 256, 0, stream>>>(pz, Zinv);

        dim3 g5(16, 32);
        k_gemm2_mfma<<<g5, 256, 0, stream>>>(softT, colsT, Zinv, patchT);
        k_col2im<<<(C_ * H_ * W_) / 256, 256, 0, stream>>>(patchT, out + (size_t)b * C_ * H_ * W_);
    }
}

// Round 7
// 674.949 us; speedup vs baseline: 1.2837x; 1.2837x over previous
//
#include <hip/hip_runtime.h>
#include <hip/hip_bf16.h>

#define B_ 2
#define C_ 64
#define H_ 128
#define W_ 128
#define HS 64
#define WS 64
#define L_ 4096
#define S_ 4096
#define K1_ 576    // C*3*3
#define NCOL 1024  // C*4*4
#define SCALE_ 10.0f

typedef __attribute__((ext_vector_type(8))) short bf16x8;
typedef __attribute__((ext_vector_type(4))) float f32x4;

// async global->LDS, 16B per lane (wave-uniform LDS base + lane*16).
__device__ __forceinline__ void async_copy16(const void* gsrc, void* ldst) {
    __builtin_amdgcn_global_load_lds(
        (__attribute__((address_space(1))) const void*)gsrc,
        (__attribute__((address_space(3))) void*)ldst, 16, 0, 0);
}

// transposed flat index within a 64x64 grid
__device__ __forceinline__ int TT(int x) { return ((x & 63) << 6) | (x >> 6); }

// fused diag_prop -> T -> diag_prop -> T, evaluated pointwise from raw scores (single batch)
__device__ __forceinline__ float diag9(const float* __restrict__ inb, int l, int s) {
    int tl = TT(l), ts = TT(s);
    float acc = 0.f;
#pragma unroll
    for (int d2 = -1; d2 <= 1; ++d2) {
        int p = tl + d2, q = ts + d2;
        if (p < 0 || p >= 4096 || q < 0 || q >= 4096) continue;
        int l2 = TT(p), s2 = TT(q);
#pragma unroll
        for (int d1 = -1; d1 <= 1; ++d1) {
            int a = l2 + d1, c2 = s2 + d1;
            if (a >= 0 && a < 4096 && c2 >= 0 && c2 < 4096) acc += inb[((size_t)a << 12) + c2];
        }
    }
    return acc;
}

// ---------------- K0a: per-pixel channel sum-of-squares of downsampled bg ----------------
__global__ void k_sumsq(const float* __restrict__ bg, float* __restrict__ ssq) {
    int idx = blockIdx.x * 256 + threadIdx.x;  // B*64*64
    if (idx >= B_ * HS * WS) return;
    int pix = idx & 4095, b = idx >> 12;
    int i = pix >> 6, j = pix & 63;
    float ss = 0.f;
    for (int c = 0; c < C_; ++c) {
        float v = bg[((b * C_ + c) * H_ + 2 * i) * W_ + 2 * j];
        ss += v * v;
    }
    ssq[idx] = ss;
}

// ---------------- K0b: per-patch mask flag + 1/denom (3x3 box) ----------------
__global__ void k_patch_stats(const float* __restrict__ mask, const float* __restrict__ ssq,
                              float* __restrict__ denom_inv, float* __restrict__ maskedf) {
    int idx = blockIdx.x * 256 + threadIdx.x;  // B*L
    if (idx >= B_ * L_) return;
    int b = idx >> 12, l = idx & 4095, lh = l >> 6, lw = l & 63;
    float msum = 0.f, ss = 0.f;
    for (int di = -1; di <= 1; ++di)
        for (int dj = -1; dj <= 1; ++dj) {
            int i = lh + di, j = lw + dj;
            if (i >= 0 && i < HS && j >= 0 && j < WS) {
                msum += mask[(b * H_ + 2 * i) * W_ + 2 * j];
                ss += ssq[(b << 12) + (i << 6) + j];
            }
        }
    maskedf[idx] = (msum == 0.0f) ? 1.0f : 0.0f;
    denom_inv[idx] = 1.0f / fmaxf(sqrtf(ss), 0.001f);
}

// ---------------- K0c: im2col (3x3, pad 1, on 2x-downsampled img) -> hi/lo bf16 [l][576] ----
__global__ void k_im2col(const float* __restrict__ src, __hip_bfloat16* __restrict__ hi,
                         __hip_bfloat16* __restrict__ lo) {
    int idx = blockIdx.x * 256 + threadIdx.x;  // L*576, k fastest
    int k = idx % K1_;
    int l = idx / K1_;
    int c = k / 9, r = k - 9 * c;
    int r3 = r / 3;
    int di = r3 - 1, dj = r - 3 * r3 - 1;
    int i = (l >> 6) + di, j = (l & 63) + dj;
    float v = 0.f;
    if (i >= 0 && i < HS && j >= 0 && j < WS) v = src[(c * H_ + 2 * i) * W_ + 2 * j];
    __hip_bfloat16 h = __float2bfloat16(v);
    hi[idx] = h;
    lo[idx] = __float2bfloat16(v - __bfloat162float(h));
}

// ---------------- K1: scores GEMM, split-bf16 MFMA (fp32-equivalent), single batch --------
__global__ __launch_bounds__(256) void k_gemm1_mfma(const __hip_bfloat16* __restrict__ Ahi,
                                                    const __hip_bfloat16* __restrict__ Alo,
                                                    const __hip_bfloat16* __restrict__ Bhi,
                                                    const __hip_bfloat16* __restrict__ Blo,
                                                    const float* __restrict__ dinv,
                                                    float* __restrict__ scores) {
    __shared__ __hip_bfloat16 AsH[128 * 32], AsL[128 * 32], BsH[128 * 32], BsL[128 * 32];
    int t = threadIdx.x, lane = t & 63, w = t >> 6;
    int wm = w & 1, wn = w >> 1;
    int M0 = blockIdx.y * 128, N0 = blockIdx.x * 128;
    int srow = lane >> 2, schunk = (lane & 3) * 8;
    f32x4 acc[4][4] = {};
    for (int k0 = 0; k0 < K1_; k0 += 32) {
#pragma unroll
        for (int q = 0; q < 2; ++q) {
            int r = q * 64 + w * 16;
            size_t ga = (size_t)(M0 + r + srow) * K1_ + k0 + schunk;
            size_t gb = (size_t)(N0 + r + srow) * K1_ + k0 + schunk;
            int lo_ = r * 32;
            async_copy16(Ahi + ga, &AsH[lo_]);
            async_copy16(Alo + ga, &AsL[lo_]);
            async_copy16(Bhi + gb, &BsH[lo_]);
            async_copy16(Blo + gb, &BsL[lo_]);
        }
        __syncthreads();
        int q8 = (lane >> 4) * 8, mr = lane & 15;
        bf16x8 ah[4], al[4], bh[4], bl[4];
#pragma unroll
        for (int i = 0; i < 4; ++i) {
            int ra = (wm * 64 + i * 16 + mr) * 32 + q8;
            int rb = (wn * 64 + i * 16 + mr) * 32 + q8;
            ah[i] = *(const bf16x8*)&AsH[ra];
            al[i] = *(const bf16x8*)&AsL[ra];
            bh[i] = *(const bf16x8*)&BsH[rb];
            bl[i] = *(const bf16x8*)&BsL[rb];
        }
#pragma unroll
        for (int mt = 0; mt < 4; ++mt)
#pragma unroll
            for (int nt = 0; nt < 4; ++nt) {
                acc[mt][nt] = __builtin_amdgcn_mfma_f32_16x16x32_bf16(ah[mt], bh[nt], acc[mt][nt], 0, 0, 0);
                acc[mt][nt] = __builtin_amdgcn_mfma_f32_16x16x32_bf16(ah[mt], bl[nt], acc[mt][nt], 0, 0, 0);
                acc[mt][nt] = __builtin_amdgcn_mfma_f32_16x16x32_bf16(al[mt], bh[nt], acc[mt][nt], 0, 0, 0);
            }
        __syncthreads();
    }
    int col = lane & 15, rq = (lane >> 4) * 4;
#pragma unroll
    for (int mt = 0; mt < 4; ++mt)
#pragma unroll
        for (int r = 0; r < 4; ++r) {
            int m = M0 + wm * 64 + mt * 16 + rq + r;
            float dv = dinv[m];
#pragma unroll
            for (int nt = 0; nt < 4; ++nt) {
                int n = N0 + wn * 64 + nt * 16 + col;
                scores[(size_t)m * 4096 + n] = acc[mt][nt][r] * dv;
            }
        }
}

// ---------------- K2: diag9 -> LOCAL-max softmax tile -> transpose -> softT (UNNORM) ------
// grid (64 s-tiles, 64 l-tiles). One diag9 evaluation total; no global-max pass.
// Writes pml[lblk][s] (local max), pz[lblk][s] (local Z), softT[s][l] = exp(10(v - m_loc)).
__global__ __launch_bounds__(256) void k_soft_local(const float* __restrict__ scores,
                                                    const float* __restrict__ maskedf,
                                                    __hip_bfloat16* __restrict__ softT,
                                                    float* __restrict__ pml,
                                                    float* __restrict__ pz) {
    __shared__ float tile[64][65];
    __shared__ float tmax[4][64];
    __shared__ float zpart[4][64];
    int t = threadIdx.x;
    int sx = t & 63, tg = t >> 6;
    int s0 = blockIdx.x * 64, l0 = blockIdx.y * 64;
    int s = s0 + sx;
    // phase 1: diag9 into LDS + per-thread max
    float tmx = -3.0e38f;
#pragma unroll 4
    for (int i = 0; i < 16; ++i) {
        int lloc = tg * 16 + i;
        int l = l0 + lloc;
        float v = (maskedf[l] != 0.f) ? -1000.f : diag9(scores, l, s);
        tile[lloc][sx] = v;
        tmx = fmaxf(tmx, v);
    }
    tmax[tg][sx] = tmx;
    __syncthreads();
    float mloc = fmaxf(fmaxf(tmax[0][sx], tmax[1][sx]), fmaxf(tmax[2][sx], tmax[3][sx]));
    // phase 2: exponentiate vs local max (e <= 1), accumulate local Z
    float zsum = 0.f;
#pragma unroll
    for (int i = 0; i < 16; ++i) {
        int lloc = tg * 16 + i;
        float e = __expf(SCALE_ * (tile[lloc][sx] - mloc));
        tile[lloc][sx] = e;
        zsum += e;
    }
    zpart[tg][sx] = zsum;
    __syncthreads();
    if (tg == 0) {
        int lblk = l0 >> 6;
        pml[(lblk << 12) + s] = mloc;
        pz[(lblk << 12) + s] = zpart[0][sx] + zpart[1][sx] + zpart[2][sx] + zpart[3][sx];
    }
    // phase 3: transposed bf16 store
#pragma unroll
    for (int i = 0; i < 16; ++i) {
        int sloc = tg * 16 + i;
        softT[((size_t)(s0 + sloc) << 12) + l0 + sx] = __float2bfloat16(tile[sx][sloc]);
    }
}

// ---------------- K3: global fixup: M, fac[c][s]=exp(10(pml-M)), Zinv ----------------
__global__ void k_zfix(const float* __restrict__ pml, const float* __restrict__ pz,
                       float* __restrict__ fac, float* __restrict__ Zinv) {
    int s = blockIdx.x * 256 + threadIdx.x;  // 4096
    float gm = -3.0e38f;
#pragma unroll 4
    for (int c = 0; c < 64; ++c) gm = fmaxf(gm, pml[(c << 12) + s]);
    float gz = 0.f;
#pragma unroll 4
    for (int c = 0; c < 64; ++c) {
        float fc = __expf(SCALE_ * (pml[(c << 12) + s] - gm));
        fac[(c << 12) + s] = fc;
        gz += pz[(c << 12) + s] * fc;
    }
    Zinv[s] = 1.0f / gz;
}

// ---------------- K3b: softT[s][l] *= fac[l>>6][s] (bf16x8 streaming) ----------------
__global__ void k_rescale(__hip_bfloat16* __restrict__ softT, const float* __restrict__ fac) {
    int idx = blockIdx.x * 256 + threadIdx.x;  // 2,097,152 (x8 elements)
    size_t base = (size_t)idx << 3;
    int l = (int)(base & 4095), s = (int)(base >> 12);
    float f = fac[((l >> 6) << 12) + s];
    bf16x8 v = *(const bf16x8*)(softT + base);
    bf16x8 o;
#pragma unroll
    for (int k = 0; k < 8; ++k) {
        unsigned short us = (unsigned short)v[k];
        float x = __uint_as_float((unsigned)us << 16) * f;
        __hip_bfloat16 r = __float2bfloat16(x);
        o[k] = *reinterpret_cast<short*>(&r);
    }
    *(bf16x8*)(softT + base) = o;
}

// ---------------- K5: cols_T[n][l] bf16 (4x4 bg patches, stride 2, pad 1), single batch ---
__global__ void k_colsT(const float* __restrict__ bgb, __hip_bfloat16* __restrict__ colsT) {
    int idx = blockIdx.x * 256 + threadIdx.x;  // NCOL*L, l fastest
    int l = idx & 4095, n = idx >> 12;
    int kj = n & 3, ki = (n >> 2) & 3, c = n >> 4;
    int y = 2 * (l >> 6) + ki - 1, x = 2 * (l & 63) + kj - 1;
    float v = 0.f;
    if (y >= 0 && y < H_ && x >= 0 && x < W_) v = bgb[(c * H_ + y) * W_ + x];
    colsT[idx] = __float2bfloat16(v);
}

// ---------------- K6: deconv GEMM, bf16 MFMA, 128x64 tiles; epilogue x Zinv[row] ----------
__global__ __launch_bounds__(256) void k_gemm2_mfma(const __hip_bfloat16* __restrict__ softT,
                                                    const __hip_bfloat16* __restrict__ colsT,
                                                    const float* __restrict__ Zinv,
                                                    float* __restrict__ patchT) {
    __shared__ __hip_bfloat16 As[128 * 32], Bs[64 * 32];
    int t = threadIdx.x, lane = t & 63, w = t >> 6;
    int wm = w & 1, wn = w >> 1;
    int M0 = blockIdx.y * 128, N0 = blockIdx.x * 64;
    int srow = lane >> 2, schunk = (lane & 3) * 8;
    f32x4 acc[4][2] = {};
    for (int k0 = 0; k0 < L_; k0 += 32) {
#pragma unroll
        for (int q = 0; q < 2; ++q) {
            int r = q * 64 + w * 16;
            async_copy16(softT + ((size_t)(M0 + r + srow) << 12) + k0 + schunk, &As[r * 32]);
        }
        {
            int r = w * 16;
            async_copy16(colsT + ((size_t)(N0 + r + srow) << 12) + k0 + schunk, &Bs[r * 32]);
        }
        __syncthreads();
        int q8 = (lane >> 4) * 8, mr = lane & 15;
        bf16x8 af[4], bfr[2];
#pragma unroll
        for (int i = 0; i < 4; ++i) af[i] = *(const bf16x8*)&As[(wm * 64 + i * 16 + mr) * 32 + q8];
#pragma unroll
        for (int j = 0; j < 2; ++j) bfr[j] = *(const bf16x8*)&Bs[(wn * 32 + j * 16 + mr) * 32 + q8];
#pragma unroll
        for (int mt = 0; mt < 4; ++mt)
#pragma unroll
            for (int nt = 0; nt < 2; ++nt)
                acc[mt][nt] = __builtin_amdgcn_mfma_f32_16x16x32_bf16(af[mt], bfr[nt], acc[mt][nt], 0, 0, 0);
        __syncthreads();
    }
    int col = lane & 15, rq = (lane >> 4) * 4;
#pragma unroll
    for (int mt = 0; mt < 4; ++mt)
#pragma unroll
        for (int r = 0; r < 4; ++r) {
            int m = M0 + wm * 64 + mt * 16 + rq + r;
            float zi = Zinv[m];
#pragma unroll
            for (int nt = 0; nt < 2; ++nt) {
                int n = N0 + wn * 32 + nt * 16 + col;
                patchT[(size_t)m * 1024 + n] = acc[mt][nt][r] * zi;
            }
        }
}

// ---------------- K7: overlap-add gather (col2im, stride 2, kernel 4, pad 1), single batch
__global__ void k_col2im(const float* __restrict__ patchT, float* __restrict__ outb) {
    int idx = blockIdx.x * 256 + threadIdx.x;  // C*H*W
    if (idx >= C_ * H_ * W_) return;
    int x = idx & 127, y = (idx >> 7) & 127, c = idx >> 14;
    float acc = 0.f;
    int ki0 = (y + 1) & 1, kj0 = (x + 1) & 1;
#pragma unroll
    for (int ki = ki0; ki < 4; ki += 2) {
        int i = (y + 1 - ki) >> 1;
        if (i < 0 || i >= HS) continue;
#pragma unroll
        for (int kj = kj0; kj < 4; kj += 2) {
            int j = (x + 1 - kj) >> 1;
            if (j < 0 || j >= WS) continue;
            acc += patchT[((size_t)(i * 64 + j) << 10) + c * 16 + ki * 4 + kj];
        }
    }
    outb[idx] = acc;
}

extern "C" void kernel_launch(void* const* d_in, const int* in_sizes, int n_in,
                              void* d_out, int out_size, void* d_ws, size_t ws_size,
                              hipStream_t stream) {
    (void)in_sizes; (void)n_in; (void)out_size; (void)ws_size;
    const float* fg = (const float*)d_in[0];
    const float* bg = (const float*)d_in[1];
    const float* mask = (const float*)d_in[2];
    float* out = (float*)d_out;

    // ---- workspace (float offsets); ~156 MiB envelope ----
    float* ws = (float*)d_ws;
    float* pml = ws;                                             // 262,144 (64 x 4096)
    float* pz = ws + 262144;                                     // 262,144
    float* fac = ws + 524288;                                    // 262,144
    __hip_bfloat16* softT = (__hip_bfloat16*)(ws + 1048576);     // 16,777,216 bf16 (= 8,388,608 f)
    float* scores = ws + 16777216;                               // 16,777,216 f
    float* patchT = ws + 25165824;                               // 4,194,304 f (in scores region; scores dead by gemm2)
    __hip_bfloat16* colsT = (__hip_bfloat16*)(ws + 33554432);    // 4,194,304 bf16
    __hip_bfloat16* bgcol_hi = (__hip_bfloat16*)(ws + 35651584); // 2,359,296 bf16 each
    __hip_bfloat16* bgcol_lo = (__hip_bfloat16*)(ws + 36831232);
    __hip_bfloat16* fgcol_hi = (__hip_bfloat16*)(ws + 38010880);
    __hip_bfloat16* fgcol_lo = (__hip_bfloat16*)(ws + 39190528);
    float* denom_inv = ws + 40370176;  // 8,192 (B*L)
    float* maskedf = ws + 40378368;    // 8,192 (B*L)
    float* ssq = ws + 40386560;        // 8,192
    float* Zinv = ws + 40398848;       // 4,096

    k_sumsq<<<(B_ * HS * WS) / 256, 256, 0, stream>>>(bg, ssq);
    k_patch_stats<<<(B_ * L_) / 256, 256, 0, stream>>>(mask, ssq, denom_inv, maskedf);

    for (int b = 0; b < B_; ++b) {
        const float* bgb = bg + (size_t)b * C_ * H_ * W_;
        const float* fgb = fg + (size_t)b * C_ * H_ * W_;

        k_im2col<<<(L_ * K1_) / 256, 256, 0, stream>>>(bgb, bgcol_hi, bgcol_lo);
        k_im2col<<<(L_ * K1_) / 256, 256, 0, stream>>>(fgb, fgcol_hi, fgcol_lo);
        k_colsT<<<(NCOL * L_) / 256, 256, 0, stream>>>(bgb, colsT);

        dim3 g1(32, 32);
        k_gemm1_mfma<<<g1, 256, 0, stream>>>(bgcol_hi, bgcol_lo, fgcol_hi, fgcol_lo,
                                             denom_inv + b * L_, scores);

        dim3 g4(64, 64);
        k_soft_local<<<g4, 256, 0, stream>>>(scores, maskedf + b * L_, softT, pml, pz);
        k_zfix<<<16, 256, 0, stream>>>(pml, pz, fac, Zinv);
        k_rescale<<<8192, 256, 0, stream>>>(softT, fac);

        dim3 g5(16, 32);
        k_gemm2_mfma<<<g5, 256, 0, stream>>>(softT, colsT, Zinv, patchT);
        k_col2im<<<(C_ * H_ * W_) / 256, 256, 0, stream>>>(patchT, out + (size_t)b * C_ * H_ * W_);
    }
}

// Round 8
// 629.729 us; speedup vs baseline: 1.3759x; 1.0718x over previous
//
#include <hip/hip_runtime.h>
#include <hip/hip_bf16.h>

#define B_ 2
#define C_ 64
#define H_ 128
#define W_ 128
#define HS 64
#define WS 64
#define L_ 4096
#define S_ 4096
#define K1_ 576    // C*3*3
#define NCOL 1024  // C*4*4
#define SCALE_ 10.0f

typedef __attribute__((ext_vector_type(8))) short bf16x8;
typedef __attribute__((ext_vector_type(4))) float f32x4;

// async global->LDS, 16B per lane (wave-uniform LDS base + lane*16).
__device__ __forceinline__ void async_copy16(const void* gsrc, void* ldst) {
    __builtin_amdgcn_global_load_lds(
        (__attribute__((address_space(1))) const void*)gsrc,
        (__attribute__((address_space(3))) void*)ldst, 16, 0, 0);
}

// transposed flat index within a 64x64 grid
__device__ __forceinline__ int TT(int x) { return ((x & 63) << 6) | (x >> 6); }

// generic 3-tap (d2) gather over Y with exact TT boundary semantics
__device__ __forceinline__ float diag3Y(const float* __restrict__ Y, int l, int s) {
    int tl = TT(l), ts = TT(s);
    float acc = 0.f;
#pragma unroll
    for (int d2 = -1; d2 <= 1; ++d2) {
        int p = tl + d2, q = ts + d2;
        if ((unsigned)p < 4096u && (unsigned)q < 4096u)
            acc += Y[((size_t)TT(p) << 12) + TT(q)];
    }
    return acc;
}

// ---------------- K0a: per-pixel channel sum-of-squares of downsampled bg ----------------
__global__ void k_sumsq(const float* __restrict__ bg, float* __restrict__ ssq) {
    int idx = blockIdx.x * 256 + threadIdx.x;  // B*64*64
    if (idx >= B_ * HS * WS) return;
    int pix = idx & 4095, b = idx >> 12;
    int i = pix >> 6, j = pix & 63;
    float ss = 0.f;
    for (int c = 0; c < C_; ++c) {
        float v = bg[((b * C_ + c) * H_ + 2 * i) * W_ + 2 * j];
        ss += v * v;
    }
    ssq[idx] = ss;
}

// ---------------- K0b: per-patch mask flag + 1/denom (3x3 box) ----------------
__global__ void k_patch_stats(const float* __restrict__ mask, const float* __restrict__ ssq,
                              float* __restrict__ denom_inv, float* __restrict__ maskedf) {
    int idx = blockIdx.x * 256 + threadIdx.x;  // B*L
    if (idx >= B_ * L_) return;
    int b = idx >> 12, l = idx & 4095, lh = l >> 6, lw = l & 63;
    float msum = 0.f, ss = 0.f;
    for (int di = -1; di <= 1; ++di)
        for (int dj = -1; dj <= 1; ++dj) {
            int i = lh + di, j = lw + dj;
            if (i >= 0 && i < HS && j >= 0 && j < WS) {
                msum += mask[(b * H_ + 2 * i) * W_ + 2 * j];
                ss += ssq[(b << 12) + (i << 6) + j];
            }
        }
    maskedf[idx] = (msum == 0.0f) ? 1.0f : 0.0f;
    denom_inv[idx] = 1.0f / fmaxf(sqrtf(ss), 0.001f);
}

// ---------------- K0c: fused im2col for bg AND fg (3x3, pad 1, 2x-downsampled) ----------
__global__ void k_im2col2(const float* __restrict__ bgb, const float* __restrict__ fgb,
                          __hip_bfloat16* __restrict__ bhi, __hip_bfloat16* __restrict__ blo,
                          __hip_bfloat16* __restrict__ fhi, __hip_bfloat16* __restrict__ flo) {
    int idx = blockIdx.x * 256 + threadIdx.x;  // 2*L*576
    int which = idx >= L_ * K1_;               // block-uniform (exact division)
    int id = which ? idx - L_ * K1_ : idx;
    const float* src = which ? fgb : bgb;
    __hip_bfloat16* hi = which ? fhi : bhi;
    __hip_bfloat16* lo = which ? flo : blo;
    int k = id % K1_;
    int l = id / K1_;
    int c = k / 9, r = k - 9 * c;
    int r3 = r / 3;
    int di = r3 - 1, dj = r - 3 * r3 - 1;
    int i = (l >> 6) + di, j = (l & 63) + dj;
    float v = 0.f;
    if (i >= 0 && i < HS && j >= 0 && j < WS) v = src[(c * H_ + 2 * i) * W_ + 2 * j];
    __hip_bfloat16 h = __float2bfloat16(v);
    hi[id] = h;
    lo[id] = __float2bfloat16(v - __bfloat162float(h));
}

// ---------------- K1: scores GEMM, split-bf16 MFMA (fp32-equivalent), single batch --------
__global__ __launch_bounds__(256) void k_gemm1_mfma(const __hip_bfloat16* __restrict__ Ahi,
                                                    const __hip_bfloat16* __restrict__ Alo,
                                                    const __hip_bfloat16* __restrict__ Bhi,
                                                    const __hip_bfloat16* __restrict__ Blo,
                                                    const float* __restrict__ dinv,
                                                    float* __restrict__ scores) {
    __shared__ __hip_bfloat16 AsH[128 * 32], AsL[128 * 32], BsH[128 * 32], BsL[128 * 32];
    int t = threadIdx.x, lane = t & 63, w = t >> 6;
    int wm = w & 1, wn = w >> 1;
    int M0 = blockIdx.y * 128, N0 = blockIdx.x * 128;
    int srow = lane >> 2, schunk = (lane & 3) * 8;
    f32x4 acc[4][4] = {};
    for (int k0 = 0; k0 < K1_; k0 += 32) {
#pragma unroll
        for (int q = 0; q < 2; ++q) {
            int r = q * 64 + w * 16;
            size_t ga = (size_t)(M0 + r + srow) * K1_ + k0 + schunk;
            size_t gb = (size_t)(N0 + r + srow) * K1_ + k0 + schunk;
            int lo_ = r * 32;
            async_copy16(Ahi + ga, &AsH[lo_]);
            async_copy16(Alo + ga, &AsL[lo_]);
            async_copy16(Bhi + gb, &BsH[lo_]);
            async_copy16(Blo + gb, &BsL[lo_]);
        }
        __syncthreads();
        int q8 = (lane >> 4) * 8, mr = lane & 15;
        bf16x8 ah[4], al[4], bh[4], bl[4];
#pragma unroll
        for (int i = 0; i < 4; ++i) {
            int ra = (wm * 64 + i * 16 + mr) * 32 + q8;
            int rb = (wn * 64 + i * 16 + mr) * 32 + q8;
            ah[i] = *(const bf16x8*)&AsH[ra];
            al[i] = *(const bf16x8*)&AsL[ra];
            bh[i] = *(const bf16x8*)&BsH[rb];
            bl[i] = *(const bf16x8*)&BsL[rb];
        }
#pragma unroll
        for (int mt = 0; mt < 4; ++mt)
#pragma unroll
            for (int nt = 0; nt < 4; ++nt) {
                acc[mt][nt] = __builtin_amdgcn_mfma_f32_16x16x32_bf16(ah[mt], bh[nt], acc[mt][nt], 0, 0, 0);
                acc[mt][nt] = __builtin_amdgcn_mfma_f32_16x16x32_bf16(ah[mt], bl[nt], acc[mt][nt], 0, 0, 0);
                acc[mt][nt] = __builtin_amdgcn_mfma_f32_16x16x32_bf16(al[mt], bh[nt], acc[mt][nt], 0, 0, 0);
            }
        __syncthreads();
    }
    int col = lane & 15, rq = (lane >> 4) * 4;
#pragma unroll
    for (int mt = 0; mt < 4; ++mt)
#pragma unroll
        for (int r = 0; r < 4; ++r) {
            int m = M0 + wm * 64 + mt * 16 + rq + r;
            float dv = dinv[m];
#pragma unroll
            for (int nt = 0; nt < 4; ++nt) {
                int n = N0 + wn * 64 + nt * 16 + col;
                scores[(size_t)m * 4096 + n] = acc[mt][nt][r] * dv;
            }
        }
}

// ---------------- K2a: pass1 — flat diagonal 3-tap: Y[a][c] = sum_d1 scores[a+d1][c+d1] ---
__global__ __launch_bounds__(256) void k_pass1(const float* __restrict__ scores,
                                               float* __restrict__ Y) {
    int gid = blockIdx.x * 256 + threadIdx.x;  // 4096 rows x 1024 f4-cols
    int c4 = gid & 1023, a = gid >> 10;
    int lane = threadIdx.x & 63;
    const float* r0 = scores + ((size_t)a << 12);
    float4 Bv = ((const float4*)r0)[c4];
    float amx = 0.f, amy = 0.f, amz = 0.f, amw = 0.f;
    float cpx = 0.f, cpy = 0.f, cpz = 0.f, cpw = 0.f;
    if (a > 0) {
        const float* rm = r0 - 4096;
        float4 A = ((const float4*)rm)[c4];
        float prev = __shfl_up(A.w, 1);
        if (lane == 0) prev = (c4 > 0) ? rm[4 * c4 - 1] : 0.f;
        amx = prev; amy = A.x; amz = A.y; amw = A.z;
    }
    if (a < 4095) {
        const float* rp = r0 + 4096;
        float4 Cv = ((const float4*)rp)[c4];
        float nxt = __shfl_down(Cv.x, 1);
        if (lane == 63) nxt = (c4 < 1023) ? rp[4 * c4 + 4] : 0.f;
        cpx = Cv.y; cpy = Cv.z; cpz = Cv.w; cpw = nxt;
    }
    float4 o;
    o.x = amx + Bv.x + cpx;
    o.y = amy + Bv.y + cpy;
    o.z = amz + Bv.z + cpz;
    o.w = amw + Bv.w + cpw;
    ((float4*)(Y + ((size_t)a << 12)))[c4] = o;
}

// ---------------- K2b: pass2 — 3-tap (rows +-64) + local-max exp + transpose -> softT -----
// grid (64 s-tiles, 64 l-tiles), block 256 = (sx4 0..15) x (lg 0..15); thread: 4 l x 4 s.
__global__ __launch_bounds__(256) void k_soft3(const float* __restrict__ Y,
                                               const float* __restrict__ maskedf,
                                               __hip_bfloat16* __restrict__ softT,
                                               float* __restrict__ pml, float* __restrict__ pz) {
    __shared__ float tile[64][65];
    __shared__ float red[16][64];
    __shared__ float mloc[64];
    int t = threadIdx.x;
    int sx4 = t & 15, lg = t >> 4;
    int bx = blockIdx.x, by = blockIdx.y;
    int s0 = bx * 64, l0 = by * 64;
    bool interior = (bx >= 1) && (bx <= 62) && (by >= 1) && (by <= 62);
    float p0 = -3.0e38f, p1 = -3.0e38f, p2 = -3.0e38f, p3 = -3.0e38f;
    // phase 1: 3-tap gather into tile + per-thread column maxes
    if (interior) {
#pragma unroll
        for (int j = 0; j < 4; ++j) {
            int lloc = lg + 16 * j;
            int l = l0 + lloc;
            float a0 = 0.f, a1 = 0.f, a2 = 0.f, a3 = 0.f;
#pragma unroll
            for (int d2 = -1; d2 <= 1; ++d2) {
                const float* p = Y + ((size_t)(64 * (by + d2) + lloc) << 12) + 64 * (bx + d2) + 4 * sx4;
                float4 v = *(const float4*)p;
                a0 += v.x; a1 += v.y; a2 += v.z; a3 += v.w;
            }
            if (maskedf[l] != 0.f) { a0 = -1000.f; a1 = -1000.f; a2 = -1000.f; a3 = -1000.f; }
            tile[lloc][4 * sx4 + 0] = a0;
            tile[lloc][4 * sx4 + 1] = a1;
            tile[lloc][4 * sx4 + 2] = a2;
            tile[lloc][4 * sx4 + 3] = a3;
            p0 = fmaxf(p0, a0); p1 = fmaxf(p1, a1); p2 = fmaxf(p2, a2); p3 = fmaxf(p3, a3);
        }
    } else {
#pragma unroll
        for (int j = 0; j < 4; ++j) {
            int lloc = lg + 16 * j;
            int l = l0 + lloc;
            bool mk = (maskedf[l] != 0.f);
            float a0 = mk ? -1000.f : diag3Y(Y, l, s0 + 4 * sx4 + 0);
            float a1 = mk ? -1000.f : diag3Y(Y, l, s0 + 4 * sx4 + 1);
            float a2 = mk ? -1000.f : diag3Y(Y, l, s0 + 4 * sx4 + 2);
            float a3 = mk ? -1000.f : diag3Y(Y, l, s0 + 4 * sx4 + 3);
            tile[lloc][4 * sx4 + 0] = a0;
            tile[lloc][4 * sx4 + 1] = a1;
            tile[lloc][4 * sx4 + 2] = a2;
            tile[lloc][4 * sx4 + 3] = a3;
            p0 = fmaxf(p0, a0); p1 = fmaxf(p1, a1); p2 = fmaxf(p2, a2); p3 = fmaxf(p3, a3);
        }
    }
    red[lg][4 * sx4 + 0] = p0;
    red[lg][4 * sx4 + 1] = p1;
    red[lg][4 * sx4 + 2] = p2;
    red[lg][4 * sx4 + 3] = p3;
    __syncthreads();
    // phase 1.6: reduce 16 partials -> local max per s; write pml
    if (t < 64) {
        float m = -3.0e38f;
#pragma unroll
        for (int g = 0; g < 16; ++g) m = fmaxf(m, red[g][t]);
        mloc[t] = m;
        pml[(by << 12) + s0 + t] = m;
    }
    __syncthreads();
    // phase 2: exp vs local max, accumulate Z partials
    float m0 = mloc[4 * sx4 + 0], m1 = mloc[4 * sx4 + 1], m2 = mloc[4 * sx4 + 2], m3 = mloc[4 * sx4 + 3];
    float z0 = 0.f, z1 = 0.f, z2 = 0.f, z3 = 0.f;
#pragma unroll
    for (int j = 0; j < 4; ++j) {
        int lloc = lg + 16 * j;
        float e0 = __expf(SCALE_ * (tile[lloc][4 * sx4 + 0] - m0));
        float e1 = __expf(SCALE_ * (tile[lloc][4 * sx4 + 1] - m1));
        float e2 = __expf(SCALE_ * (tile[lloc][4 * sx4 + 2] - m2));
        float e3 = __expf(SCALE_ * (tile[lloc][4 * sx4 + 3] - m3));
        tile[lloc][4 * sx4 + 0] = e0;
        tile[lloc][4 * sx4 + 1] = e1;
        tile[lloc][4 * sx4 + 2] = e2;
        tile[lloc][4 * sx4 + 3] = e3;
        z0 += e0; z1 += e1; z2 += e2; z3 += e3;
    }
    red[lg][4 * sx4 + 0] = z0;
    red[lg][4 * sx4 + 1] = z1;
    red[lg][4 * sx4 + 2] = z2;
    red[lg][4 * sx4 + 3] = z3;
    __syncthreads();
    if (t < 64) {
        float zz = 0.f;
#pragma unroll
        for (int g = 0; g < 16; ++g) zz += red[g][t];
        pz[(by << 12) + s0 + t] = zz;
    }
    // phase 3: transposed bf16 store (tile fully updated before the barrier above)
    int sxx = t & 63, tg4 = t >> 6;
#pragma unroll
    for (int i = 0; i < 16; ++i) {
        int sloc = tg4 * 16 + i;
        softT[((size_t)(s0 + sloc) << 12) + l0 + sxx] = __float2bfloat16(tile[sxx][sloc]);
    }
}

// ---------------- K3: global fixup: M, fac[c][s]=exp(10(pml-M)), Zinv ----------------
__global__ void k_zfix(const float* __restrict__ pml, const float* __restrict__ pz,
                       float* __restrict__ fac, float* __restrict__ Zinv) {
    int s = blockIdx.x * 256 + threadIdx.x;  // 4096
    float gm = -3.0e38f;
#pragma unroll 4
    for (int c = 0; c < 64; ++c) gm = fmaxf(gm, pml[(c << 12) + s]);
    float gz = 0.f;
#pragma unroll 4
    for (int c = 0; c < 64; ++c) {
        float fc = __expf(SCALE_ * (pml[(c << 12) + s] - gm));
        fac[(c << 12) + s] = fc;
        gz += pz[(c << 12) + s] * fc;
    }
    Zinv[s] = 1.0f / gz;
}

// ---------------- K3b: softT[s][l] *= fac[l>>6][s] (bf16x8 streaming) ----------------
__global__ void k_rescale(__hip_bfloat16* __restrict__ softT, const float* __restrict__ fac) {
    int idx = blockIdx.x * 256 + threadIdx.x;  // 2,097,152 (x8 elements)
    size_t base = (size_t)idx << 3;
    int l = (int)(base & 4095), s = (int)(base >> 12);
    float f = fac[((l >> 6) << 12) + s];
    bf16x8 v = *(const bf16x8*)(softT + base);
    bf16x8 o;
#pragma unroll
    for (int k = 0; k < 8; ++k) {
        unsigned short us = (unsigned short)v[k];
        float x = __uint_as_float((unsigned)us << 16) * f;
        __hip_bfloat16 r = __float2bfloat16(x);
        o[k] = *reinterpret_cast<short*>(&r);
    }
    *(bf16x8*)(softT + base) = o;
}

// ---------------- K5: cols_T[n][l] bf16 (4x4 bg patches, stride 2, pad 1), single batch ---
__global__ void k_colsT(const float* __restrict__ bgb, __hip_bfloat16* __restrict__ colsT) {
    int idx = blockIdx.x * 256 + threadIdx.x;  // NCOL*L, l fastest
    int l = idx & 4095, n = idx >> 12;
    int kj = n & 3, ki = (n >> 2) & 3, c = n >> 4;
    int y = 2 * (l >> 6) + ki - 1, x = 2 * (l & 63) + kj - 1;
    float v = 0.f;
    if (y >= 0 && y < H_ && x >= 0 && x < W_) v = bgb[(c * H_ + y) * W_ + x];
    colsT[idx] = __float2bfloat16(v);
}

// ---------------- K6: deconv GEMM, bf16 MFMA, 128x64 tiles; epilogue x Zinv[row] ----------
__global__ __launch_bounds__(256) void k_gemm2_mfma(const __hip_bfloat16* __restrict__ softT,
                                                    const __hip_bfloat16* __restrict__ colsT,
                                                    const float* __restrict__ Zinv,
                                                    float* __restrict__ patchT) {
    __shared__ __hip_bfloat16 As[128 * 32], Bs[64 * 32];
    int t = threadIdx.x, lane = t & 63, w = t >> 6;
    int wm = w & 1, wn = w >> 1;
    int M0 = blockIdx.y * 128, N0 = blockIdx.x * 64;
    int srow = lane >> 2, schunk = (lane & 3) * 8;
    f32x4 acc[4][2] = {};
    for (int k0 = 0; k0 < L_; k0 += 32) {
#pragma unroll
        for (int q = 0; q < 2; ++q) {
            int r = q * 64 + w * 16;
            async_copy16(softT + ((size_t)(M0 + r + srow) << 12) + k0 + schunk, &As[r * 32]);
        }
        {
            int r = w * 16;
            async_copy16(colsT + ((size_t)(N0 + r + srow) << 12) + k0 + schunk, &Bs[r * 32]);
        }
        __syncthreads();
        int q8 = (lane >> 4) * 8, mr = lane & 15;
        bf16x8 af[4], bfr[2];
#pragma unroll
        for (int i = 0; i < 4; ++i) af[i] = *(const bf16x8*)&As[(wm * 64 + i * 16 + mr) * 32 + q8];
#pragma unroll
        for (int j = 0; j < 2; ++j) bfr[j] = *(const bf16x8*)&Bs[(wn * 32 + j * 16 + mr) * 32 + q8];
#pragma unroll
        for (int mt = 0; mt < 4; ++mt)
#pragma unroll
            for (int nt = 0; nt < 2; ++nt)
                acc[mt][nt] = __builtin_amdgcn_mfma_f32_16x16x32_bf16(af[mt], bfr[nt], acc[mt][nt], 0, 0, 0);
        __syncthreads();
    }
    int col = lane & 15, rq = (lane >> 4) * 4;
#pragma unroll
    for (int mt = 0; mt < 4; ++mt)
#pragma unroll
        for (int r = 0; r < 4; ++r) {
            int m = M0 + wm * 64 + mt * 16 + rq + r;
            float zi = Zinv[m];
#pragma unroll
            for (int nt = 0; nt < 2; ++nt) {
                int n = N0 + wn * 32 + nt * 16 + col;
                patchT[(size_t)m * 1024 + n] = acc[mt][nt][r] * zi;
            }
        }
}

// ---------------- K7: overlap-add gather (col2im, stride 2, kernel 4, pad 1), single batch
__global__ void k_col2im(const float* __restrict__ patchT, float* __restrict__ outb) {
    int idx = blockIdx.x * 256 + threadIdx.x;  // C*H*W
    if (idx >= C_ * H_ * W_) return;
    int x = idx & 127, y = (idx >> 7) & 127, c = idx >> 14;
    float acc = 0.f;
    int ki0 = (y + 1) & 1, kj0 = (x + 1) & 1;
#pragma unroll
    for (int ki = ki0; ki < 4; ki += 2) {
        int i = (y + 1 - ki) >> 1;
        if (i < 0 || i >= HS) continue;
#pragma unroll
        for (int kj = kj0; kj < 4; kj += 2) {
            int j = (x + 1 - kj) >> 1;
            if (j < 0 || j >= WS) continue;
            acc += patchT[((size_t)(i * 64 + j) << 10) + c * 16 + ki * 4 + kj];
        }
    }
    outb[idx] = acc;
}

extern "C" void kernel_launch(void* const* d_in, const int* in_sizes, int n_in,
                              void* d_out, int out_size, void* d_ws, size_t ws_size,
                              hipStream_t stream) {
    (void)in_sizes; (void)n_in; (void)out_size; (void)ws_size;
    const float* fg = (const float*)d_in[0];
    const float* bg = (const float*)d_in[1];
    const float* mask = (const float*)d_in[2];
    float* out = (float*)d_out;

    // ---- workspace (float offsets), total ~44.86M f = 171.1 MiB ----
    float* ws = (float*)d_ws;
    float* scores = ws;                                          // 16,777,216 f
    float* patchT = ws;                                          // alias (scores dead after pass1)
    float* Y = ws + 16777216;                                    // 16,777,216 f
    // im2col buffers alias the Y region (dead after gemm1, before pass1 writes Y)
    __hip_bfloat16* bgcol_hi = (__hip_bfloat16*)(ws + 16777216);
    __hip_bfloat16* bgcol_lo = (__hip_bfloat16*)(ws + 17956864);
    __hip_bfloat16* fgcol_hi = (__hip_bfloat16*)(ws + 19136512);
    __hip_bfloat16* fgcol_lo = (__hip_bfloat16*)(ws + 20316160);
    __hip_bfloat16* softT = (__hip_bfloat16*)(ws + 33554432);    // 16,777,216 bf16
    __hip_bfloat16* colsT = (__hip_bfloat16*)(ws + 41943040);    // 4,194,304 bf16
    float* pml = ws + 44040192;        // 262,144 (64 x 4096)
    float* pz = ws + 44302336;         // 262,144
    float* fac = ws + 44564480;        // 262,144
    float* denom_inv = ws + 44826624;  // 8,192 (B*L)
    float* maskedf = ws + 44834816;    // 8,192 (B*L)
    float* ssq = ws + 44843008;        // 8,192
    float* Zinv = ws + 44851200;       // 4,096

    k_sumsq<<<(B_ * HS * WS) / 256, 256, 0, stream>>>(bg, ssq);
    k_patch_stats<<<(B_ * L_) / 256, 256, 0, stream>>>(mask, ssq, denom_inv, maskedf);

    for (int b = 0; b < B_; ++b) {
        const float* bgb = bg + (size_t)b * C_ * H_ * W_;
        const float* fgb = fg + (size_t)b * C_ * H_ * W_;

        k_im2col2<<<(2 * L_ * K1_) / 256, 256, 0, stream>>>(bgb, fgb, bgcol_hi, bgcol_lo,
                                                            fgcol_hi, fgcol_lo);
        k_colsT<<<(NCOL * L_) / 256, 256, 0, stream>>>(bgb, colsT);

        dim3 g1(32, 32);
        k_gemm1_mfma<<<g1, 256, 0, stream>>>(bgcol_hi, bgcol_lo, fgcol_hi, fgcol_lo,
                                             denom_inv + b * L_, scores);

        k_pass1<<<(L_ * S_ / 4) / 256, 256, 0, stream>>>(scores, Y);

        dim3 g4(64, 64);
        k_soft3<<<g4, 256, 0, stream>>>(Y, maskedf + b * L_, softT, pml, pz);
        k_zfix<<<16, 256, 0, stream>>>(pml, pz, fac, Zinv);
        k_rescale<<<8192, 256, 0, stream>>>(softT, fac);

        dim3 g5(16, 32);
        k_gemm2_mfma<<<g5, 256, 0, stream>>>(softT, colsT, Zinv, patchT);
        k_col2im<<<(C_ * H_ * W_) / 256, 256, 0, stream>>>(patchT, out + (size_t)b * C_ * H_ * W_);
    }
}

// Round 9
// 627.601 us; speedup vs baseline: 1.3806x; 1.0034x over previous
//
#include <hip/hip_runtime.h>
#include <hip/hip_bf16.h>

#define B_ 2
#define C_ 64
#define H_ 128
#define W_ 128
#define HS 64
#define WS 64
#define L_ 4096
#define S_ 4096
#define K1_ 576    // C*3*3
#define NCOL 1024  // C*4*4
#define SCALE_ 10.0f

typedef __attribute__((ext_vector_type(8))) short bf16x8;
typedef __attribute__((ext_vector_type(4))) float f32x4;

// async global->LDS, 16B per lane (wave-uniform LDS base + lane*16).
__device__ __forceinline__ void async_copy16(const void* gsrc, void* ldst) {
    __builtin_amdgcn_global_load_lds(
        (__attribute__((address_space(1))) const void*)gsrc,
        (__attribute__((address_space(3))) void*)ldst, 16, 0, 0);
}

// LDS bank-conflict XOR swizzle: row R's 16B chunk c stored at position c ^ sig(R).
// sig = (R + R/4) & 3 makes each quarter-wave's 16 fragment readers cover all 8
// four-bank groups exactly twice (2-way = free, vs 8-way unswizzled).
__device__ __forceinline__ int sig(int r) { return (r + (r >> 2)) & 3; }

// transposed flat index within a 64x64 grid
__device__ __forceinline__ int TT(int x) { return ((x & 63) << 6) | (x >> 6); }

// generic 3-tap (d2) gather over Y with exact TT boundary semantics
__device__ __forceinline__ float diag3Y(const float* __restrict__ Y, int l, int s) {
    int tl = TT(l), ts = TT(s);
    float acc = 0.f;
#pragma unroll
    for (int d2 = -1; d2 <= 1; ++d2) {
        int p = tl + d2, q = ts + d2;
        if ((unsigned)p < 4096u && (unsigned)q < 4096u)
            acc += Y[((size_t)TT(p) << 12) + TT(q)];
    }
    return acc;
}

// ---------------- K0a: per-pixel channel sum-of-squares of downsampled bg ----------------
__global__ void k_sumsq(const float* __restrict__ bg, float* __restrict__ ssq) {
    int idx = blockIdx.x * 256 + threadIdx.x;  // B*64*64
    if (idx >= B_ * HS * WS) return;
    int pix = idx & 4095, b = idx >> 12;
    int i = pix >> 6, j = pix & 63;
    float ss = 0.f;
    for (int c = 0; c < C_; ++c) {
        float v = bg[((b * C_ + c) * H_ + 2 * i) * W_ + 2 * j];
        ss += v * v;
    }
    ssq[idx] = ss;
}

// ---------------- K0b: per-patch mask flag + 1/denom (3x3 box) ----------------
__global__ void k_patch_stats(const float* __restrict__ mask, const float* __restrict__ ssq,
                              float* __restrict__ denom_inv, float* __restrict__ maskedf) {
    int idx = blockIdx.x * 256 + threadIdx.x;  // B*L
    if (idx >= B_ * L_) return;
    int b = idx >> 12, l = idx & 4095, lh = l >> 6, lw = l & 63;
    float msum = 0.f, ss = 0.f;
    for (int di = -1; di <= 1; ++di)
        for (int dj = -1; dj <= 1; ++dj) {
            int i = lh + di, j = lw + dj;
            if (i >= 0 && i < HS && j >= 0 && j < WS) {
                msum += mask[(b * H_ + 2 * i) * W_ + 2 * j];
                ss += ssq[(b << 12) + (i << 6) + j];
            }
        }
    maskedf[idx] = (msum == 0.0f) ? 1.0f : 0.0f;
    denom_inv[idx] = 1.0f / fmaxf(sqrtf(ss), 0.001f);
}

// ---------------- K0c: fused im2col for bg AND fg (3x3, pad 1, 2x-downsampled) ----------
__global__ void k_im2col2(const float* __restrict__ bgb, const float* __restrict__ fgb,
                          __hip_bfloat16* __restrict__ bhi, __hip_bfloat16* __restrict__ blo,
                          __hip_bfloat16* __restrict__ fhi, __hip_bfloat16* __restrict__ flo) {
    int idx = blockIdx.x * 256 + threadIdx.x;  // 2*L*576
    int which = idx >= L_ * K1_;               // block-uniform (exact division)
    int id = which ? idx - L_ * K1_ : idx;
    const float* src = which ? fgb : bgb;
    __hip_bfloat16* hi = which ? fhi : bhi;
    __hip_bfloat16* lo = which ? flo : blo;
    int k = id % K1_;
    int l = id / K1_;
    int c = k / 9, r = k - 9 * c;
    int r3 = r / 3;
    int di = r3 - 1, dj = r - 3 * r3 - 1;
    int i = (l >> 6) + di, j = (l & 63) + dj;
    float v = 0.f;
    if (i >= 0 && i < HS && j >= 0 && j < WS) v = src[(c * H_ + 2 * i) * W_ + 2 * j];
    __hip_bfloat16 h = __float2bfloat16(v);
    hi[id] = h;
    lo[id] = __float2bfloat16(v - __bfloat162float(h));
}

// ---------------- K1: scores GEMM, split-bf16 MFMA (fp32-equivalent), single batch --------
__global__ __launch_bounds__(256) void k_gemm1_mfma(const __hip_bfloat16* __restrict__ Ahi,
                                                    const __hip_bfloat16* __restrict__ Alo,
                                                    const __hip_bfloat16* __restrict__ Bhi,
                                                    const __hip_bfloat16* __restrict__ Blo,
                                                    const float* __restrict__ dinv,
                                                    float* __restrict__ scores) {
    __shared__ __hip_bfloat16 AsH[128 * 32], AsL[128 * 32], BsH[128 * 32], BsL[128 * 32];
    int t = threadIdx.x, lane = t & 63, w = t >> 6;
    int wm = w & 1, wn = w >> 1;
    int M0 = blockIdx.y * 128, N0 = blockIdx.x * 128;
    int srow = lane >> 2;
    f32x4 acc[4][4] = {};
    for (int k0 = 0; k0 < K1_; k0 += 32) {
#pragma unroll
        for (int q = 0; q < 2; ++q) {
            int r = q * 64 + w * 16;
            int row = r + srow;
            int sch = (((lane & 3) ^ sig(row)) << 3);  // swizzled source chunk
            size_t ga = (size_t)(M0 + row) * K1_ + k0 + sch;
            size_t gb = (size_t)(N0 + row) * K1_ + k0 + sch;
            int lo_ = r * 32;
            async_copy16(Ahi + ga, &AsH[lo_]);
            async_copy16(Alo + ga, &AsL[lo_]);
            async_copy16(Bhi + gb, &BsH[lo_]);
            async_copy16(Blo + gb, &BsL[lo_]);
        }
        __syncthreads();
        int qc = lane >> 4, mr = lane & 15;
        bf16x8 ah[4], al[4], bh[4], bl[4];
#pragma unroll
        for (int i = 0; i < 4; ++i) {
            int rowa = wm * 64 + i * 16 + mr;
            int rowb = wn * 64 + i * 16 + mr;
            int ra = rowa * 32 + ((qc ^ sig(rowa)) << 3);
            int rb = rowb * 32 + ((qc ^ sig(rowb)) << 3);
            ah[i] = *(const bf16x8*)&AsH[ra];
            al[i] = *(const bf16x8*)&AsL[ra];
            bh[i] = *(const bf16x8*)&BsH[rb];
            bl[i] = *(const bf16x8*)&BsL[rb];
        }
#pragma unroll
        for (int mt = 0; mt < 4; ++mt)
#pragma unroll
            for (int nt = 0; nt < 4; ++nt) {
                acc[mt][nt] = __builtin_amdgcn_mfma_f32_16x16x32_bf16(ah[mt], bh[nt], acc[mt][nt], 0, 0, 0);
                acc[mt][nt] = __builtin_amdgcn_mfma_f32_16x16x32_bf16(ah[mt], bl[nt], acc[mt][nt], 0, 0, 0);
                acc[mt][nt] = __builtin_amdgcn_mfma_f32_16x16x32_bf16(al[mt], bh[nt], acc[mt][nt], 0, 0, 0);
            }
        __syncthreads();
    }
    int col = lane & 15, rq = (lane >> 4) * 4;
#pragma unroll
    for (int mt = 0; mt < 4; ++mt)
#pragma unroll
        for (int r = 0; r < 4; ++r) {
            int m = M0 + wm * 64 + mt * 16 + rq + r;
            float dv = dinv[m];
#pragma unroll
            for (int nt = 0; nt < 4; ++nt) {
                int n = N0 + wn * 64 + nt * 16 + col;
                scores[(size_t)m * 4096 + n] = acc[mt][nt][r] * dv;
            }
        }
}

// ---------------- K2a: pass1 — flat diagonal 3-tap: Y[a][c] = sum_d1 scores[a+d1][c+d1] ---
__global__ __launch_bounds__(256) void k_pass1(const float* __restrict__ scores,
                                               float* __restrict__ Y) {
    int gid = blockIdx.x * 256 + threadIdx.x;  // 4096 rows x 1024 f4-cols
    int c4 = gid & 1023, a = gid >> 10;
    int lane = threadIdx.x & 63;
    const float* r0 = scores + ((size_t)a << 12);
    float4 Bv = ((const float4*)r0)[c4];
    float amx = 0.f, amy = 0.f, amz = 0.f, amw = 0.f;
    float cpx = 0.f, cpy = 0.f, cpz = 0.f, cpw = 0.f;
    if (a > 0) {
        const float* rm = r0 - 4096;
        float4 A = ((const float4*)rm)[c4];
        float prev = __shfl_up(A.w, 1);
        if (lane == 0) prev = (c4 > 0) ? rm[4 * c4 - 1] : 0.f;
        amx = prev; amy = A.x; amz = A.y; amw = A.z;
    }
    if (a < 4095) {
        const float* rp = r0 + 4096;
        float4 Cv = ((const float4*)rp)[c4];
        float nxt = __shfl_down(Cv.x, 1);
        if (lane == 63) nxt = (c4 < 1023) ? rp[4 * c4 + 4] : 0.f;
        cpx = Cv.y; cpy = Cv.z; cpz = Cv.w; cpw = nxt;
    }
    float4 o;
    o.x = amx + Bv.x + cpx;
    o.y = amy + Bv.y + cpy;
    o.z = amz + Bv.z + cpz;
    o.w = amw + Bv.w + cpw;
    ((float4*)(Y + ((size_t)a << 12)))[c4] = o;
}

// ---------------- K2b: pass2 — 3-tap (rows +-64) + local-max exp + transpose -> softT -----
__global__ __launch_bounds__(256) void k_soft3(const float* __restrict__ Y,
                                               const float* __restrict__ maskedf,
                                               __hip_bfloat16* __restrict__ softT,
                                               float* __restrict__ pml, float* __restrict__ pz) {
    __shared__ float tile[64][65];
    __shared__ float red[16][64];
    __shared__ float mloc[64];
    int t = threadIdx.x;
    int sx4 = t & 15, lg = t >> 4;
    int bx = blockIdx.x, by = blockIdx.y;
    int s0 = bx * 64, l0 = by * 64;
    bool interior = (bx >= 1) && (bx <= 62) && (by >= 1) && (by <= 62);
    float p0 = -3.0e38f, p1 = -3.0e38f, p2 = -3.0e38f, p3 = -3.0e38f;
    if (interior) {
#pragma unroll
        for (int j = 0; j < 4; ++j) {
            int lloc = lg + 16 * j;
            int l = l0 + lloc;
            float a0 = 0.f, a1 = 0.f, a2 = 0.f, a3 = 0.f;
#pragma unroll
            for (int d2 = -1; d2 <= 1; ++d2) {
                const float* p = Y + ((size_t)(64 * (by + d2) + lloc) << 12) + 64 * (bx + d2) + 4 * sx4;
                float4 v = *(const float4*)p;
                a0 += v.x; a1 += v.y; a2 += v.z; a3 += v.w;
            }
            if (maskedf[l] != 0.f) { a0 = -1000.f; a1 = -1000.f; a2 = -1000.f; a3 = -1000.f; }
            tile[lloc][4 * sx4 + 0] = a0;
            tile[lloc][4 * sx4 + 1] = a1;
            tile[lloc][4 * sx4 + 2] = a2;
            tile[lloc][4 * sx4 + 3] = a3;
            p0 = fmaxf(p0, a0); p1 = fmaxf(p1, a1); p2 = fmaxf(p2, a2); p3 = fmaxf(p3, a3);
        }
    } else {
#pragma unroll
        for (int j = 0; j < 4; ++j) {
            int lloc = lg + 16 * j;
            int l = l0 + lloc;
            bool mk = (maskedf[l] != 0.f);
            float a0 = mk ? -1000.f : diag3Y(Y, l, s0 + 4 * sx4 + 0);
            float a1 = mk ? -1000.f : diag3Y(Y, l, s0 + 4 * sx4 + 1);
            float a2 = mk ? -1000.f : diag3Y(Y, l, s0 + 4 * sx4 + 2);
            float a3 = mk ? -1000.f : diag3Y(Y, l, s0 + 4 * sx4 + 3);
            tile[lloc][4 * sx4 + 0] = a0;
            tile[lloc][4 * sx4 + 1] = a1;
            tile[lloc][4 * sx4 + 2] = a2;
            tile[lloc][4 * sx4 + 3] = a3;
            p0 = fmaxf(p0, a0); p1 = fmaxf(p1, a1); p2 = fmaxf(p2, a2); p3 = fmaxf(p3, a3);
        }
    }
    red[lg][4 * sx4 + 0] = p0;
    red[lg][4 * sx4 + 1] = p1;
    red[lg][4 * sx4 + 2] = p2;
    red[lg][4 * sx4 + 3] = p3;
    __syncthreads();
    if (t < 64) {
        float m = -3.0e38f;
#pragma unroll
        for (int g = 0; g < 16; ++g) m = fmaxf(m, red[g][t]);
        mloc[t] = m;
        pml[(by << 12) + s0 + t] = m;
    }
    __syncthreads();
    float m0 = mloc[4 * sx4 + 0], m1 = mloc[4 * sx4 + 1], m2 = mloc[4 * sx4 + 2], m3 = mloc[4 * sx4 + 3];
    float z0 = 0.f, z1 = 0.f, z2 = 0.f, z3 = 0.f;
#pragma unroll
    for (int j = 0; j < 4; ++j) {
        int lloc = lg + 16 * j;
        float e0 = __expf(SCALE_ * (tile[lloc][4 * sx4 + 0] - m0));
        float e1 = __expf(SCALE_ * (tile[lloc][4 * sx4 + 1] - m1));
        float e2 = __expf(SCALE_ * (tile[lloc][4 * sx4 + 2] - m2));
        float e3 = __expf(SCALE_ * (tile[lloc][4 * sx4 + 3] - m3));
        tile[lloc][4 * sx4 + 0] = e0;
        tile[lloc][4 * sx4 + 1] = e1;
        tile[lloc][4 * sx4 + 2] = e2;
        tile[lloc][4 * sx4 + 3] = e3;
        z0 += e0; z1 += e1; z2 += e2; z3 += e3;
    }
    red[lg][4 * sx4 + 0] = z0;
    red[lg][4 * sx4 + 1] = z1;
    red[lg][4 * sx4 + 2] = z2;
    red[lg][4 * sx4 + 3] = z3;
    __syncthreads();
    if (t < 64) {
        float zz = 0.f;
#pragma unroll
        for (int g = 0; g < 16; ++g) zz += red[g][t];
        pz[(by << 12) + s0 + t] = zz;
    }
    int sxx = t & 63, tg4 = t >> 6;
#pragma unroll
    for (int i = 0; i < 16; ++i) {
        int sloc = tg4 * 16 + i;
        softT[((size_t)(s0 + sloc) << 12) + l0 + sxx] = __float2bfloat16(tile[sxx][sloc]);
    }
}

// ---------------- K3: global fixup: M, fac[c][s]=exp(10(pml-M)), Zinv ----------------
__global__ void k_zfix(const float* __restrict__ pml, const float* __restrict__ pz,
                       float* __restrict__ fac, float* __restrict__ Zinv) {
    int s = blockIdx.x * 256 + threadIdx.x;  // 4096
    float gm = -3.0e38f;
#pragma unroll 4
    for (int c = 0; c < 64; ++c) gm = fmaxf(gm, pml[(c << 12) + s]);
    float gz = 0.f;
#pragma unroll 4
    for (int c = 0; c < 64; ++c) {
        float fc = __expf(SCALE_ * (pml[(c << 12) + s] - gm));
        fac[(c << 12) + s] = fc;
        gz += pz[(c << 12) + s] * fc;
    }
    Zinv[s] = 1.0f / gz;
}

// ---------------- K3b: softT[s][l] *= fac[l>>6][s] (bf16x8 streaming) ----------------
__global__ void k_rescale(__hip_bfloat16* __restrict__ softT, const float* __restrict__ fac) {
    int idx = blockIdx.x * 256 + threadIdx.x;  // 2,097,152 (x8 elements)
    size_t base = (size_t)idx << 3;
    int l = (int)(base & 4095), s = (int)(base >> 12);
    float f = fac[((l >> 6) << 12) + s];
    bf16x8 v = *(const bf16x8*)(softT + base);
    bf16x8 o;
#pragma unroll
    for (int k = 0; k < 8; ++k) {
        unsigned short us = (unsigned short)v[k];
        float x = __uint_as_float((unsigned)us << 16) * f;
        __hip_bfloat16 r = __float2bfloat16(x);
        o[k] = *reinterpret_cast<short*>(&r);
    }
    *(bf16x8*)(softT + base) = o;
}

// ---------------- K5: cols_T[n][l] bf16 (4x4 bg patches, stride 2, pad 1), single batch ---
__global__ void k_colsT(const float* __restrict__ bgb, __hip_bfloat16* __restrict__ colsT) {
    int idx = blockIdx.x * 256 + threadIdx.x;  // NCOL*L, l fastest
    int l = idx & 4095, n = idx >> 12;
    int kj = n & 3, ki = (n >> 2) & 3, c = n >> 4;
    int y = 2 * (l >> 6) + ki - 1, x = 2 * (l & 63) + kj - 1;
    float v = 0.f;
    if (y >= 0 && y < H_ && x >= 0 && x < W_) v = bgb[(c * H_ + y) * W_ + x];
    colsT[idx] = __float2bfloat16(v);
}

// ---------------- K6: deconv GEMM, bf16 MFMA, 128x64 tiles; epilogue x Zinv[row] ----------
__global__ __launch_bounds__(256) void k_gemm2_mfma(const __hip_bfloat16* __restrict__ softT,
                                                    const __hip_bfloat16* __restrict__ colsT,
                                                    const float* __restrict__ Zinv,
                                                    float* __restrict__ patchT) {
    __shared__ __hip_bfloat16 As[128 * 32], Bs[64 * 32];
    int t = threadIdx.x, lane = t & 63, w = t >> 6;
    int wm = w & 1, wn = w >> 1;
    int M0 = blockIdx.y * 128, N0 = blockIdx.x * 64;
    int srow = lane >> 2;
    f32x4 acc[4][2] = {};
    for (int k0 = 0; k0 < L_; k0 += 32) {
#pragma unroll
        for (int q = 0; q < 2; ++q) {
            int r = q * 64 + w * 16;
            int row = r + srow;
            int sch = (((lane & 3) ^ sig(row)) << 3);
            async_copy16(softT + ((size_t)(M0 + row) << 12) + k0 + sch, &As[r * 32]);
        }
        {
            int r = w * 16;
            int row = r + srow;
            int sch = (((lane & 3) ^ sig(row)) << 3);
            async_copy16(colsT + ((size_t)(N0 + row) << 12) + k0 + sch, &Bs[r * 32]);
        }
        __syncthreads();
        int qc = lane >> 4, mr = lane & 15;
        bf16x8 af[4], bfr[2];
#pragma unroll
        for (int i = 0; i < 4; ++i) {
            int rowa = wm * 64 + i * 16 + mr;
            af[i] = *(const bf16x8*)&As[rowa * 32 + ((qc ^ sig(rowa)) << 3)];
        }
#pragma unroll
        for (int j = 0; j < 2; ++j) {
            int rowb = wn * 32 + j * 16 + mr;
            bfr[j] = *(const bf16x8*)&Bs[rowb * 32 + ((qc ^ sig(rowb)) << 3)];
        }
#pragma unroll
        for (int mt = 0; mt < 4; ++mt)
#pragma unroll
            for (int nt = 0; nt < 2; ++nt)
                acc[mt][nt] = __builtin_amdgcn_mfma_f32_16x16x32_bf16(af[mt], bfr[nt], acc[mt][nt], 0, 0, 0);
        __syncthreads();
    }
    int col = lane & 15, rq = (lane >> 4) * 4;
#pragma unroll
    for (int mt = 0; mt < 4; ++mt)
#pragma unroll
        for (int r = 0; r < 4; ++r) {
            int m = M0 + wm * 64 + mt * 16 + rq + r;
            float zi = Zinv[m];
#pragma unroll
            for (int nt = 0; nt < 2; ++nt) {
                int n = N0 + wn * 32 + nt * 16 + col;
                patchT[(size_t)m * 1024 + n] = acc[mt][nt][r] * zi;
            }
        }
}

// ---------------- K7: overlap-add gather (col2im, stride 2, kernel 4, pad 1), single batch
__global__ void k_col2im(const float* __restrict__ patchT, float* __restrict__ outb) {
    int idx = blockIdx.x * 256 + threadIdx.x;  // C*H*W
    if (idx >= C_ * H_ * W_) return;
    int x = idx & 127, y = (idx >> 7) & 127, c = idx >> 14;
    float acc = 0.f;
    int ki0 = (y + 1) & 1, kj0 = (x + 1) & 1;
#pragma unroll
    for (int ki = ki0; ki < 4; ki += 2) {
        int i = (y + 1 - ki) >> 1;
        if (i < 0 || i >= HS) continue;
#pragma unroll
        for (int kj = kj0; kj < 4; kj += 2) {
            int j = (x + 1 - kj) >> 1;
            if (j < 0 || j >= WS) continue;
            acc += patchT[((size_t)(i * 64 + j) << 10) + c * 16 + ki * 4 + kj];
        }
    }
    outb[idx] = acc;
}

extern "C" void kernel_launch(void* const* d_in, const int* in_sizes, int n_in,
                              void* d_out, int out_size, void* d_ws, size_t ws_size,
                              hipStream_t stream) {
    (void)in_sizes; (void)n_in; (void)out_size; (void)ws_size;
    const float* fg = (const float*)d_in[0];
    const float* bg = (const float*)d_in[1];
    const float* mask = (const float*)d_in[2];
    float* out = (float*)d_out;

    // ---- workspace (float offsets), total ~44.86M f = 171.1 MiB ----
    float* ws = (float*)d_ws;
    float* scores = ws;                                          // 16,777,216 f
    float* patchT = ws;                                          // alias (scores dead after pass1)
    float* Y = ws + 16777216;                                    // 16,777,216 f
    __hip_bfloat16* bgcol_hi = (__hip_bfloat16*)(ws + 16777216); // im2col buffers alias Y region
    __hip_bfloat16* bgcol_lo = (__hip_bfloat16*)(ws + 17956864);
    __hip_bfloat16* fgcol_hi = (__hip_bfloat16*)(ws + 19136512);
    __hip_bfloat16* fgcol_lo = (__hip_bfloat16*)(ws + 20316160);
    __hip_bfloat16* softT = (__hip_bfloat16*)(ws + 33554432);    // 16,777,216 bf16
    __hip_bfloat16* colsT = (__hip_bfloat16*)(ws + 41943040);    // 4,194,304 bf16
    float* pml = ws + 44040192;        // 262,144 (64 x 4096)
    float* pz = ws + 44302336;         // 262,144
    float* fac = ws + 44564480;        // 262,144
    float* denom_inv = ws + 44826624;  // 8,192 (B*L)
    float* maskedf = ws + 44834816;    // 8,192 (B*L)
    float* ssq = ws + 44843008;        // 8,192
    float* Zinv = ws + 44851200;       // 4,096

    k_sumsq<<<(B_ * HS * WS) / 256, 256, 0, stream>>>(bg, ssq);
    k_patch_stats<<<(B_ * L_) / 256, 256, 0, stream>>>(mask, ssq, denom_inv, maskedf);

    for (int b = 0; b < B_; ++b) {
        const float* bgb = bg + (size_t)b * C_ * H_ * W_;
        const float* fgb = fg + (size_t)b * C_ * H_ * W_;

        k_im2col2<<<(2 * L_ * K1_) / 256, 256, 0, stream>>>(bgb, fgb, bgcol_hi, bgcol_lo,
                                                            fgcol_hi, fgcol_lo);
        k_colsT<<<(NCOL * L_) / 256, 256, 0, stream>>>(bgb, colsT);

        dim3 g1(32, 32);
        k_gemm1_mfma<<<g1, 256, 0, stream>>>(bgcol_hi, bgcol_lo, fgcol_hi, fgcol_lo,
                                             denom_inv + b * L_, scores);

        k_pass1<<<(L_ * S_ / 4) / 256, 256, 0, stream>>>(scores, Y);

        dim3 g4(64, 64);
        k_soft3<<<g4, 256, 0, stream>>>(Y, maskedf + b * L_, softT, pml, pz);
        k_zfix<<<16, 256, 0, stream>>>(pml, pz, fac, Zinv);
        k_rescale<<<8192, 256, 0, stream>>>(softT, fac);

        dim3 g5(16, 32);
        k_gemm2_mfma<<<g5, 256, 0, stream>>>(softT, colsT, Zinv, patchT);
        k_col2im<<<(C_ * H_ * W_) / 256, 256, 0, stream>>>(patchT, out + (size_t)b * C_ * H_ * W_);
    }
}